// Round 1
// 452.982 us; speedup vs baseline: 1.0196x; 1.0196x over previous
//
#include <hip/hip_runtime.h>
#include <math.h>

#define SQ 96            // H == W == 96
#define CQ 256
#define OQ 768           // 3*C
#define HWQ 9216         // 96*96
#define PIXQ 73728       // 8*9216

typedef __attribute__((ext_vector_type(8))) __bf16 bf16x8;
typedef __attribute__((ext_vector_type(4))) float f32x4;

union FragU { uint4 u; bf16x8 b; };

// round-to-nearest-even fp32 -> bf16 (as u16 in low bits)
__device__ inline uint32_t bf16_rne_u(float f) {
  uint32_t u = __float_as_uint(f);
  return (u + 0x7FFFu + ((u >> 16) & 1u)) >> 16;
}
// split fp32 into hi (RNE bf16) + lo (truncated bf16 of residual), packed u32
__device__ inline uint32_t pack_split(float f) {
  uint32_t hi = bf16_rne_u(f);
  float rem = f - __uint_as_float(hi << 16);
  uint32_t lo = __float_as_uint(rem) >> 16;
  return hi | (lo << 16);
}
// 8 packed u32 (2x uint4) -> hi-frag (8 bf16) and lo-frag (8 bf16)
__device__ inline void unpack_frags(uint4 r0, uint4 r1, FragU& hi, FragU& lo) {
  hi.u.x = (r0.x & 0xFFFFu) | (r0.y << 16);
  hi.u.y = (r0.z & 0xFFFFu) | (r0.w << 16);
  hi.u.z = (r1.x & 0xFFFFu) | (r1.y << 16);
  hi.u.w = (r1.z & 0xFFFFu) | (r1.w << 16);
  lo.u.x = (r0.x >> 16) | (r0.y & 0xFFFF0000u);
  lo.u.y = (r0.z >> 16) | (r0.w & 0xFFFF0000u);
  lo.u.z = (r1.x >> 16) | (r1.y & 0xFFFF0000u);
  lo.u.w = (r1.z >> 16) | (r1.w & 0xFFFF0000u);
}

// XOR-swizzled LDS addressing for [row][32 u32] tiles (128B row stride).
// byte_col bits 4..6 ^= (row&7): kills the 16-way ds_read_b128 conflict
// (all lanes of a quad read rows base+lr at a fixed column -> same bank)
// and makes the b128 staging writes conflict-free as well.
__device__ inline uint32_t* swz(uint32_t* base, int row, int colb) {
  return base + row * 32 + ((colb ^ ((row & 7) << 4)) >> 2);
}
__device__ inline const uint32_t* swzc(const uint32_t* base, int row, int colb) {
  return base + row * 32 + ((colb ^ ((row & 7) << 4)) >> 2);
}

// ---------------------------------------------------------------------------
// Pack weights: wp[o*256+c] = split(w[o][c])
// ---------------------------------------------------------------------------
__global__ __launch_bounds__(256) void pack_w_kernel(
    const float* __restrict__ w, uint32_t* __restrict__ wp) {
  int i = blockIdx.x * 256 + threadIdx.x;   // 768 blocks x 256 = 196608
  wp[i] = pack_split(w[i]);
}

// ---------------------------------------------------------------------------
// QKV GEMM via split-bf16 MFMA.  M=73728 (p=(b,w,h)), N=768, K=256.
// Block 128x128, 4 waves (2x2) of 64x64, 16x16x32 bf16 MFMA, 3 products
// (hi*hi + hi*lo + lo*hi; lo*lo ~2^-18 relative, dropped).
// 1-D grid with bijective XCD chunking, n-fastest: the 6 n-blocks of one
// m-panel run adjacently on one XCD -> x panel is read ~once from HBM.
// Outputs: q,k as packed split-u32 (qk, o<512); v as bf16 (vb).
// Stored h-major: pixel (b,h,w).
// ---------------------------------------------------------------------------
__global__ __launch_bounds__(256) void qkv_gemm_mfma(
    const float* __restrict__ x, const uint32_t* __restrict__ wp,
    const float* __restrict__ bias, uint32_t* __restrict__ qk,
    ushort* __restrict__ vb) {
  __shared__ uint32_t Apk[128 * 32];   // packed hi|lo, [m][k], swizzled
  __shared__ uint32_t Bpk[128 * 32];   // packed hi|lo, [n][k], swizzled
  const int tid = threadIdx.x;
  const int lane = tid & 63;
  const int wid = tid >> 6;
  const int wm = wid >> 1, wn = wid & 1;
  const int lr = lane & 15, quad = lane >> 4;
  // 3456 blocks = 576 m-panels x 6 n-panels; 3456/8 = 432 per XCD (exact)
  const int lin = (blockIdx.x & 7) * 432 + (blockIdx.x >> 3);
  const int m0 = (lin / 6) * 128, n0 = (lin % 6) * 128;
  const int sr = tid >> 1, skh = (tid & 1) * 16;   // staging: row, k-half

  f32x4 acc[4][4] = {};

  for (int k0 = 0; k0 < 256; k0 += 32) {
    // stage A (x) with on-the-fly split
    const float* xsrc = x + (size_t)(m0 + sr) * 256 + k0 + skh;
#pragma unroll
    for (int j = 0; j < 4; ++j) {
      float4 v = *(const float4*)(xsrc + 4 * j);
      uint4 p;
      p.x = pack_split(v.x); p.y = pack_split(v.y);
      p.z = pack_split(v.z); p.w = pack_split(v.w);
      *(uint4*)swz(Apk, sr, skh * 4 + j * 16) = p;
    }
    // stage B (wp, already packed)
    const uint32_t* wsrc = wp + (size_t)(n0 + sr) * 256 + k0 + skh;
#pragma unroll
    for (int j = 0; j < 4; ++j)
      *(uint4*)swz(Bpk, sr, skh * 4 + j * 16) = *(const uint4*)(wsrc + 4 * j);
    __syncthreads();

    FragU ah[4], al[4], bh[4], bl[4];
#pragma unroll
    for (int t = 0; t < 4; ++t) {
      const int ra = wm * 64 + t * 16 + lr;
      unpack_frags(*(const uint4*)swzc(Apk, ra, quad * 32),
                   *(const uint4*)swzc(Apk, ra, quad * 32 + 16), ah[t], al[t]);
      const int rb = wn * 64 + t * 16 + lr;
      unpack_frags(*(const uint4*)swzc(Bpk, rb, quad * 32),
                   *(const uint4*)swzc(Bpk, rb, quad * 32 + 16), bh[t], bl[t]);
    }
#pragma unroll
    for (int i = 0; i < 4; ++i)
#pragma unroll
      for (int j = 0; j < 4; ++j) {
        acc[i][j] = __builtin_amdgcn_mfma_f32_16x16x32_bf16(al[i].b, bh[j].b, acc[i][j], 0, 0, 0);
        acc[i][j] = __builtin_amdgcn_mfma_f32_16x16x32_bf16(ah[i].b, bl[j].b, acc[i][j], 0, 0, 0);
        acc[i][j] = __builtin_amdgcn_mfma_f32_16x16x32_bf16(ah[i].b, bh[j].b, acc[i][j], 0, 0, 0);
      }
    __syncthreads();
  }

  // epilogue: C[row=(quad*4+r)][col=lr] per 16x16 tile
#pragma unroll
  for (int i = 0; i < 4; ++i) {
    const int growb = m0 + wm * 64 + i * 16 + quad * 4;
#pragma unroll
    for (int r = 0; r < 4; ++r) {
      int p = growb + r;                 // input pixel order (b, w, h)
      int b = p / HWQ;
      int rem = p - b * HWQ;
      int ww = rem / SQ;
      int hh = rem - ww * SQ;
      size_t opix = (size_t)b * HWQ + (size_t)hh * SQ + ww;   // h-major
#pragma unroll
      for (int j = 0; j < 4; ++j) {
        int o = n0 + wn * 64 + j * 16 + lr;
        float val = acc[i][j][r] + bias[o];
        if (o < 512) qk[opix * 512 + o] = pack_split(val);
        else vb[opix * 256 + (o - 512)] = (ushort)bf16_rne_u(val);
      }
    }
  }
}

// ---------------------------------------------------------------------------
// Attention scores via split-bf16 MFMA, K split across 32 chunks, atomicAdd.
// which=0: Sh[b,h1,h2] = sum_{w,c} q[b,h1,w,c]*k[b,h2,w,c]
// which=1: Sw[b,w1,w2] = sum_{h,c} k[b,h,w1,c]*q[b,h,w2,c]
// qk layout: [(b*9216 + h*96 + w)*512 + o] packed u32, q:o<256, k:256+.
// Block: M=96,N=96, 4 waves (2x2) of 48x48, K=3 kouts x 256c = 768.
// ---------------------------------------------------------------------------
__global__ __launch_bounds__(256) void attn_scores_mfma(
    const uint32_t* __restrict__ qk, float* __restrict__ Sh,
    float* __restrict__ Sw) {
  __shared__ uint32_t Xpk[96 * 32];
  __shared__ uint32_t Ypk[96 * 32];
  const int tid = threadIdx.x;
  const int lane = tid & 63;
  const int wid = tid >> 6;
  const int wm = wid >> 1, wn = wid & 1;
  const int lr = lane & 15, quad = lane >> 4;
  const int chunk = blockIdx.x;      // 0..31 (3 kouts each)
  const int b = blockIdx.y;          // 0..7
  const int which = blockIdx.z;      // 0=Sh, 1=Sw
  const size_t base = (size_t)b * HWQ * 512;
  const int offX = which ? 256 : 0;
  const int offY = which ? 0 : 256;

  f32x4 acc[3][3] = {};

  for (int it = 0; it < 24; ++it) {
    int kout = chunk * 3 + (it >> 3);     // w (Sh) or h (Sw)
    int c0 = (it & 7) * 32;
#pragma unroll
    for (int j = 0; j < 3; ++j) {
      int s = j * 256 + tid;              // 0..767 uint4 slots
      int row = s >> 3;                   // 0..95
      int colb = (s & 7) * 16;
      size_t idx = which ? ((size_t)kout * SQ + row) : ((size_t)row * SQ + kout);
      const uint32_t* src = qk + base + idx * 512 + c0 + (colb >> 2);
      *(uint4*)swz(Xpk, row, colb) = *(const uint4*)(src + offX);
      *(uint4*)swz(Ypk, row, colb) = *(const uint4*)(src + offY);
    }
    __syncthreads();
    FragU xh[3], xl[3], yh[3], yl[3];
#pragma unroll
    for (int t = 0; t < 3; ++t) {
      const int rx = wm * 48 + t * 16 + lr;
      unpack_frags(*(const uint4*)swzc(Xpk, rx, quad * 32),
                   *(const uint4*)swzc(Xpk, rx, quad * 32 + 16), xh[t], xl[t]);
      const int ry = wn * 48 + t * 16 + lr;
      unpack_frags(*(const uint4*)swzc(Ypk, ry, quad * 32),
                   *(const uint4*)swzc(Ypk, ry, quad * 32 + 16), yh[t], yl[t]);
    }
#pragma unroll
    for (int i = 0; i < 3; ++i)
#pragma unroll
      for (int j = 0; j < 3; ++j) {
        acc[i][j] = __builtin_amdgcn_mfma_f32_16x16x32_bf16(xl[i].b, yh[j].b, acc[i][j], 0, 0, 0);
        acc[i][j] = __builtin_amdgcn_mfma_f32_16x16x32_bf16(xh[i].b, yl[j].b, acc[i][j], 0, 0, 0);
        acc[i][j] = __builtin_amdgcn_mfma_f32_16x16x32_bf16(xh[i].b, yh[j].b, acc[i][j], 0, 0, 0);
      }
    __syncthreads();
  }
  float* S = which ? Sw : Sh;
#pragma unroll
  for (int i = 0; i < 3; ++i)
#pragma unroll
    for (int r = 0; r < 4; ++r)
#pragma unroll
      for (int j = 0; j < 3; ++j) {
        int row = wm * 48 + i * 16 + quad * 4 + r;
        int col = wn * 48 + j * 16 + lr;
        atomicAdd(S + ((size_t)b * SQ + row) * SQ + col, acc[i][j][r]);
      }
}

// ---------------------------------------------------------------------------
// Softmax over last dim (96); emits bf16 probabilities.
// rows 0..767 -> Sh -> Pms ; rows 768..1535 -> Sw -> Pma
// ---------------------------------------------------------------------------
__global__ __launch_bounds__(256) void softmax_p(
    const float* __restrict__ Sh, const float* __restrict__ Sw,
    ushort* __restrict__ Pms, ushort* __restrict__ Pma) {
  const int tid = threadIdx.x;
  const int lane = tid & 63;
  const int row = blockIdx.x * 4 + (tid >> 6);
  const float* p = (row < 768) ? (Sh + (size_t)row * SQ)
                               : (Sw + (size_t)(row - 768) * SQ);
  ushort* q = (row < 768) ? (Pms + (size_t)row * SQ)
                          : (Pma + (size_t)(row - 768) * SQ);
  float v0 = p[lane];
  float v1 = (lane < 32) ? p[64 + lane] : -3.0e38f;
  float m = fmaxf(v0, v1);
#pragma unroll
  for (int off = 32; off > 0; off >>= 1) m = fmaxf(m, __shfl_xor(m, off));
  float e0 = __expf(v0 - m);
  float e1 = (lane < 32) ? __expf(v1 - m) : 0.0f;
  float s = e0 + e1;
#pragma unroll
  for (int off = 32; off > 0; off >>= 1) s += __shfl_xor(s, off);
  float inv = 1.0f / s;
  q[lane] = (ushort)bf16_rne_u(e0 * inv);
  if (lane < 32) q[64 + lane] = (ushort)bf16_rne_u(e1 * inv);
}

// ---------------------------------------------------------------------------
// Apply attention via single-bf16 MFMA.  out: ((b*96 + w)*96 + h)*256 + c
// which=0 (block b, xi=w): O[h][c]  = sum_h2 Pms[b,h,h2] * V[b,h2,xi,c]
// which=1 (block b, xi=h): O[w][c] += sum_w2 Pma[b,w,w2] * V[b,xi,w2,c]
// M=96, N=256, K=96.  4 waves (2x2) of 48x128.  V transposed into LDS [c][k].
// ---------------------------------------------------------------------------
__global__ __launch_bounds__(256) void attn_apply_mfma(
    const ushort* __restrict__ vb, const ushort* __restrict__ P,
    float* __restrict__ out, const int which) {
  __shared__ ushort Vt[256 * 40];      // [c][k] stride 40 (80B, 16B-mult)
  const int tid = threadIdx.x;
  const int lane = tid & 63;
  const int wid = tid >> 6;
  const int wm = wid >> 1, wn = wid & 1;
  const int lr = lane & 15, quad = lane >> 4;
  const int xi = blockIdx.x;           // w (which=0) or h (which=1)
  const int b = blockIdx.y;

  f32x4 acc[3][8] = {};

  for (int k0 = 0; k0 < 96; k0 += 32) {
    // stage V-tile (32 k x 256 c) transposed via 2x2 micro-blocks
#pragma unroll
    for (int j = 0; j < 8; ++j) {
      int bi = j * 256 + tid;          // 0..2047
      int c2 = bi & 127;               // c-pair index
      int k2 = bi >> 7;                // k-pair index 0..15
      int k = k0 + k2 * 2;
      int c = c2 * 2;
      size_t r0, r1;
      if (which == 0) {
        r0 = ((size_t)b * HWQ + (size_t)k * SQ + xi) * CQ + c;
        r1 = r0 + (size_t)SQ * CQ;
      } else {
        r0 = ((size_t)b * HWQ + (size_t)xi * SQ + k) * CQ + c;
        r1 = r0 + CQ;
      }
      uint32_t a0 = *(const uint32_t*)(vb + r0);       // V[k][c], V[k][c+1]
      uint32_t a1 = *(const uint32_t*)(vb + r1);       // V[k+1][c], V[k+1][c+1]
      uint32_t w0 = (a0 & 0xFFFFu) | (a1 << 16);       // Vt[c][k..k+1]
      uint32_t w1 = (a0 >> 16) | (a1 & 0xFFFF0000u);   // Vt[c+1][k..k+1]
      *(uint32_t*)&Vt[c * 40 + k2 * 2] = w0;
      *(uint32_t*)&Vt[(c + 1) * 40 + k2 * 2] = w1;
    }
    __syncthreads();
    // A frags straight from global P (L1/L2-hot, reused by 96 blocks)
    FragU a[3];
#pragma unroll
    for (int t = 0; t < 3; ++t) {
      int row = wm * 48 + t * 16 + lr;
      const ushort* ps = P + ((size_t)b * SQ + row) * SQ + k0 + quad * 8;
      a[t].u = *(const uint4*)ps;
    }
#pragma unroll
    for (int j = 0; j < 8; ++j) {
      int cb = wn * 128 + j * 16 + lr;
      FragU bf;
      bf.u = *(const uint4*)&Vt[cb * 40 + quad * 8];
#pragma unroll
      for (int i = 0; i < 3; ++i)
        acc[i][j] = __builtin_amdgcn_mfma_f32_16x16x32_bf16(a[i].b, bf.b, acc[i][j], 0, 0, 0);
    }
    __syncthreads();
  }

#pragma unroll
  for (int i = 0; i < 3; ++i) {
#pragma unroll
    for (int r = 0; r < 4; ++r) {
      int mrow = wm * 48 + i * 16 + quad * 4 + r;
      size_t obase;
      if (which == 0) obase = (((size_t)b * SQ + xi) * SQ + mrow) * CQ;
      else            obase = (((size_t)b * SQ + mrow) * SQ + xi) * CQ;
#pragma unroll
      for (int j = 0; j < 8; ++j) {
        int c = wn * 128 + j * 16 + lr;
        if (which == 0) out[obase + c] = acc[i][j][r];
        else            out[obase + c] += acc[i][j][r];
      }
    }
  }
}

// ---------------------------------------------------------------------------
extern "C" void kernel_launch(void* const* d_in, const int* in_sizes, int n_in,
                              void* d_out, int out_size, void* d_ws,
                              size_t ws_size, hipStream_t stream) {
  const float* x = (const float*)d_in[0];      // (8,96,96,256) = (B,W,H,C)
  const float* w = (const float*)d_in[1];      // (768,256)
  const float* bias = (const float*)d_in[2];   // (768,)
  float* out = (float*)d_out;                  // (8,96,96,256) = (B,W,H,C)

  // workspace layout (~190 MB)
  uint32_t* qk  = (uint32_t*)d_ws;                       // 73728*512 u32
  ushort*   vb  = (ushort*)(qk + (size_t)PIXQ * 512);    // 73728*256 ushort
  float*    Sh  = (float*)(vb + (size_t)PIXQ * 256);     // 73728 f32
  float*    Sw  = Sh + PIXQ;                             // 73728 f32
  ushort*   Pms = (ushort*)(Sw + PIXQ);                  // 73728 ushort
  ushort*   Pma = Pms + PIXQ;                            // 73728 ushort
  uint32_t* wp  = (uint32_t*)(Pma + PIXQ);               // 196608 u32

  hipMemsetAsync(Sh, 0, 2 * (size_t)PIXQ * sizeof(float), stream);

  pack_w_kernel<<<dim3(768), 256, 0, stream>>>(w, wp);
  qkv_gemm_mfma<<<dim3(3456), 256, 0, stream>>>(x, wp, bias, qk, vb);
  attn_scores_mfma<<<dim3(32, 8, 2), 256, 0, stream>>>(qk, Sh, Sw);
  softmax_p<<<dim3(384), 256, 0, stream>>>(Sh, Sw, Pms, Pma);
  attn_apply_mfma<<<dim3(96, 8), 256, 0, stream>>>(vb, Pms, out, 0);
  attn_apply_mfma<<<dim3(96, 8), 256, 0, stream>>>(vb, Pma, out, 1);
}

// Round 2
// 418.646 us; speedup vs baseline: 1.1032x; 1.0820x over previous
//
#include <hip/hip_runtime.h>
#include <math.h>

#define SQ 96            // H == W == 96
#define CQ 256
#define OQ 768           // 3*C
#define HWQ 9216         // 96*96
#define PIXQ 73728       // 8*9216

typedef __attribute__((ext_vector_type(8))) __bf16 bf16x8;
typedef __attribute__((ext_vector_type(4))) float f32x4;

union FragU { uint4 u; bf16x8 b; };

// round-to-nearest-even fp32 -> bf16 (as u16 in low bits)
__device__ inline uint32_t bf16_rne_u(float f) {
  uint32_t u = __float_as_uint(f);
  return (u + 0x7FFFu + ((u >> 16) & 1u)) >> 16;
}
// split fp32 into hi (RNE bf16) + lo (truncated bf16 of residual), packed u32
__device__ inline uint32_t pack_split(float f) {
  uint32_t hi = bf16_rne_u(f);
  float rem = f - __uint_as_float(hi << 16);
  uint32_t lo = __float_as_uint(rem) >> 16;
  return hi | (lo << 16);
}

// XOR-swizzled LDS read addressing for [row][128B] tiles.
// Data is stored pre-swizzled (byte pos = nominal ^ ((row&7)<<4)); the read
// applies the same involution. 2-way bank aliasing only (free on CDNA4).
__device__ inline const uint32_t* swzc(const uint32_t* base, int row, int colb) {
  return base + row * 32 + ((colb ^ ((row & 7) << 4)) >> 2);
}

// async global->LDS DMA, 16B per lane, lane-linear LDS dest
__device__ inline void lds_dma16(const void* g, void* l) {
  __builtin_amdgcn_global_load_lds(
      (const __attribute__((address_space(1))) uint32_t*)g,
      (__attribute__((address_space(3))) uint32_t*)l, 16, 0, 0);
}

// ---------------------------------------------------------------------------
// Split fp32 rows (256 ch) into tile-image records: per (row, kc) a 128B
// record = 64B hi-plane bf16[32] || 64B lo-plane bf16[32], bytes pre-swizzled
// by pos ^= ((row&7)<<4).  One thread handles 8 channels.
// Used for x (73728 rows, grid 9216) and w (768 rows, grid 96).
// ---------------------------------------------------------------------------
__global__ __launch_bounds__(256) void split_tiles_kernel(
    const float* __restrict__ src, uint32_t* __restrict__ dst) {
  int t = blockIdx.x * 256 + threadIdx.x;
  int e = t * 8;
  int m = e >> 8;
  int rem = e & 255;
  int kc = rem >> 5;
  int k8 = (rem & 31) >> 3;
  const float* s = src + (size_t)m * 256 + rem;
  uint32_t h[4], l[4];
#pragma unroll
  for (int i = 0; i < 2; ++i) {
    float4 v = *(const float4*)(s + 4 * i);
    uint32_t p0 = pack_split(v.x), p1 = pack_split(v.y);
    uint32_t p2 = pack_split(v.z), p3 = pack_split(v.w);
    h[2 * i]     = (p0 & 0xFFFFu) | (p1 << 16);
    h[2 * i + 1] = (p2 & 0xFFFFu) | (p3 << 16);
    l[2 * i]     = (p0 >> 16) | (p1 & 0xFFFF0000u);
    l[2 * i + 1] = (p2 >> 16) | (p3 & 0xFFFF0000u);
  }
  int swz = (m & 7) << 4;
  uint32_t* rowp = dst + ((size_t)m * 8 + kc) * 32;
  *(uint4*)(rowp + (((k8 * 16) ^ swz) >> 2)) = *(uint4*)h;
  *(uint4*)(rowp + (((64 + k8 * 16) ^ swz) >> 2)) = *(uint4*)l;
}

// ---------------------------------------------------------------------------
// QKV GEMM.  M=73728, N=768, K=256.  Block 128x128, 4 waves (2x2) of 64x64,
// 16x16x32 bf16 MFMA, 3 split-products.  Staging = pure global_load_lds from
// pre-split tile images (zero marshalling VALU); fragments = direct
// ds_read_b128 from hi/lo halves (no unpack).  XCD-chunked 1-D grid.
// Outputs: qkh/qkl (split planes) for q,k; vb (bf16) for v.  h-major pixels.
// ---------------------------------------------------------------------------
__global__ __launch_bounds__(256) void qkv_gemm_mfma(
    const uint32_t* __restrict__ xps, const uint32_t* __restrict__ wps,
    const float* __restrict__ bias, ushort* __restrict__ qkh,
    ushort* __restrict__ qkl, ushort* __restrict__ vb) {
  __shared__ uint32_t Apk[128 * 32];   // [m][128B = 64B hi | 64B lo], swizzled
  __shared__ uint32_t Bpk[128 * 32];
  const int tid = threadIdx.x;
  const int lane = tid & 63;
  const int wid = tid >> 6;
  const int wm = wid >> 1, wn = wid & 1;
  const int lr = lane & 15, quad = lane >> 4;
  // 3456 blocks = 576 m-panels x 6 n-panels; 432 per XCD, n-fastest
  const int lin = (blockIdx.x & 7) * 432 + (blockIdx.x >> 3);
  const int m0 = (lin / 6) * 128, n0 = (lin % 6) * 128;
  const int srow = tid >> 3;           // 0..31
  const int scol = (tid & 7) * 4;      // u32 within 128B record

  f32x4 acc[4][4] = {};

  const uint32_t* aP = xps + (size_t)(m0 + srow) * 256 + scol;
  const uint32_t* bP = wps + (size_t)(n0 + srow) * 256 + scol;

  for (int kc = 0; kc < 8; ++kc) {
#pragma unroll
    for (int j = 0; j < 4; ++j) {
      lds_dma16(aP + j * 8192 + kc * 32, &Apk[j * 1024 + tid * 4]);
      lds_dma16(bP + j * 8192 + kc * 32, &Bpk[j * 1024 + tid * 4]);
    }
    __syncthreads();

    FragU ah[4], al[4], bh[4], bl[4];
#pragma unroll
    for (int t = 0; t < 4; ++t) {
      const int ra = wm * 64 + t * 16 + lr;
      ah[t].u = *(const uint4*)swzc(Apk, ra, quad * 16);
      al[t].u = *(const uint4*)swzc(Apk, ra, 64 + quad * 16);
      const int rb = wn * 64 + t * 16 + lr;
      bh[t].u = *(const uint4*)swzc(Bpk, rb, quad * 16);
      bl[t].u = *(const uint4*)swzc(Bpk, rb, 64 + quad * 16);
    }
#pragma unroll
    for (int i = 0; i < 4; ++i)
#pragma unroll
      for (int j = 0; j < 4; ++j) {
        acc[i][j] = __builtin_amdgcn_mfma_f32_16x16x32_bf16(al[i].b, bh[j].b, acc[i][j], 0, 0, 0);
        acc[i][j] = __builtin_amdgcn_mfma_f32_16x16x32_bf16(ah[i].b, bl[j].b, acc[i][j], 0, 0, 0);
        acc[i][j] = __builtin_amdgcn_mfma_f32_16x16x32_bf16(ah[i].b, bh[j].b, acc[i][j], 0, 0, 0);
      }
    __syncthreads();
  }

  // epilogue: C[row=(quad*4+r)][col=lr] per 16x16 tile
#pragma unroll
  for (int i = 0; i < 4; ++i) {
    const int growb = m0 + wm * 64 + i * 16 + quad * 4;
#pragma unroll
    for (int r = 0; r < 4; ++r) {
      int p = growb + r;                 // input pixel order (b, w, h)
      int b = p / HWQ;
      int rem = p - b * HWQ;
      int ww = rem / SQ;
      int hh = rem - ww * SQ;
      size_t opix = (size_t)b * HWQ + (size_t)hh * SQ + ww;   // h-major
#pragma unroll
      for (int j = 0; j < 4; ++j) {
        int o = n0 + wn * 64 + j * 16 + lr;
        float val = acc[i][j][r] + bias[o];
        if (o < 512) {
          uint32_t ps = pack_split(val);
          qkh[opix * 512 + o] = (ushort)ps;
          qkl[opix * 512 + o] = (ushort)(ps >> 16);
        } else {
          vb[opix * 256 + (o - 512)] = (ushort)bf16_rne_u(val);
        }
      }
    }
  }
}

// ---------------------------------------------------------------------------
// Attention scores, K split across 32 chunks, atomicAdd.
// which=0: Sh[b,h1,h2] = sum_{w,c} q[b,h1,w,c]*k[b,h2,w,c]
// which=1: Sw[b,w1,w2] = sum_{h,c} k[b,h,w1,c]*q[b,h,w2,c]
// Staging via global_load_lds with source-side swizzle (LDS stays linear);
// fragments read hi/lo halves directly, no unpack.
// Block: M=96,N=96, 4 waves (2x2) of 48x48.
// ---------------------------------------------------------------------------
__global__ __launch_bounds__(256) void attn_scores_mfma(
    const ushort* __restrict__ qkh, const ushort* __restrict__ qkl,
    float* __restrict__ Sh, float* __restrict__ Sw) {
  __shared__ uint32_t Xpk[96 * 32];
  __shared__ uint32_t Ypk[96 * 32];
  const int tid = threadIdx.x;
  const int lane = tid & 63;
  const int wid = tid >> 6;
  const int wm = wid >> 1, wn = wid & 1;
  const int lr = lane & 15, quad = lane >> 4;
  const int chunk = blockIdx.x;      // 0..31 (3 kouts each)
  const int b = blockIdx.y;          // 0..7
  const int which = blockIdx.z;      // 0=Sh, 1=Sw
  const size_t base = (size_t)b * HWQ * 512;
  const int offX = which ? 256 : 0;
  const int offY = which ? 0 : 256;
  const int srow = tid >> 3;           // 0..31
  const int byteoff = (tid & 7) * 16;

  f32x4 acc[3][3] = {};

  for (int it = 0; it < 24; ++it) {
    int kout = chunk * 3 + (it >> 3);     // w (Sh) or h (Sw)
    int c0 = (it & 7) * 32;
#pragma unroll
    for (int j = 0; j < 3; ++j) {
      int row = j * 32 + srow;
      int nom = byteoff ^ ((row & 7) << 4);   // source-side swizzle
      const ushort* plane = (nom & 64) ? qkl : qkh;
      int within = (nom & 63) >> 1;
      size_t pix = which ? ((size_t)kout * SQ + row) : ((size_t)row * SQ + kout);
      const ushort* sX = plane + base + pix * 512 + offX + c0 + within;
      const ushort* sY = plane + base + pix * 512 + offY + c0 + within;
      lds_dma16(sX, &Xpk[j * 1024 + tid * 4]);
      lds_dma16(sY, &Ypk[j * 1024 + tid * 4]);
    }
    __syncthreads();

    FragU xh[3], xl[3], yh[3], yl[3];
#pragma unroll
    for (int t = 0; t < 3; ++t) {
      const int rx = wm * 48 + t * 16 + lr;
      xh[t].u = *(const uint4*)swzc(Xpk, rx, quad * 16);
      xl[t].u = *(const uint4*)swzc(Xpk, rx, 64 + quad * 16);
      const int ry = wn * 48 + t * 16 + lr;
      yh[t].u = *(const uint4*)swzc(Ypk, ry, quad * 16);
      yl[t].u = *(const uint4*)swzc(Ypk, ry, 64 + quad * 16);
    }
#pragma unroll
    for (int i = 0; i < 3; ++i)
#pragma unroll
      for (int j = 0; j < 3; ++j) {
        acc[i][j] = __builtin_amdgcn_mfma_f32_16x16x32_bf16(xl[i].b, yh[j].b, acc[i][j], 0, 0, 0);
        acc[i][j] = __builtin_amdgcn_mfma_f32_16x16x32_bf16(xh[i].b, yl[j].b, acc[i][j], 0, 0, 0);
        acc[i][j] = __builtin_amdgcn_mfma_f32_16x16x32_bf16(xh[i].b, yh[j].b, acc[i][j], 0, 0, 0);
      }
    __syncthreads();
  }
  float* S = which ? Sw : Sh;
#pragma unroll
  for (int i = 0; i < 3; ++i)
#pragma unroll
    for (int r = 0; r < 4; ++r)
#pragma unroll
      for (int j = 0; j < 3; ++j) {
        int row = wm * 48 + i * 16 + quad * 4 + r;
        int col = wn * 48 + j * 16 + lr;
        atomicAdd(S + ((size_t)b * SQ + row) * SQ + col, acc[i][j][r]);
      }
}

// ---------------------------------------------------------------------------
// Softmax over last dim (96); emits bf16 probabilities.
// rows 0..767 -> Sh -> Pms ; rows 768..1535 -> Sw -> Pma
// ---------------------------------------------------------------------------
__global__ __launch_bounds__(256) void softmax_p(
    const float* __restrict__ Sh, const float* __restrict__ Sw,
    ushort* __restrict__ Pms, ushort* __restrict__ Pma) {
  const int tid = threadIdx.x;
  const int lane = tid & 63;
  const int row = blockIdx.x * 4 + (tid >> 6);
  const float* p = (row < 768) ? (Sh + (size_t)row * SQ)
                               : (Sw + (size_t)(row - 768) * SQ);
  ushort* q = (row < 768) ? (Pms + (size_t)row * SQ)
                          : (Pma + (size_t)(row - 768) * SQ);
  float v0 = p[lane];
  float v1 = (lane < 32) ? p[64 + lane] : -3.0e38f;
  float m = fmaxf(v0, v1);
#pragma unroll
  for (int off = 32; off > 0; off >>= 1) m = fmaxf(m, __shfl_xor(m, off));
  float e0 = __expf(v0 - m);
  float e1 = (lane < 32) ? __expf(v1 - m) : 0.0f;
  float s = e0 + e1;
#pragma unroll
  for (int off = 32; off > 0; off >>= 1) s += __shfl_xor(s, off);
  float inv = 1.0f / s;
  q[lane] = (ushort)bf16_rne_u(e0 * inv);
  if (lane < 32) q[64 + lane] = (ushort)bf16_rne_u(e1 * inv);
}

// ---------------------------------------------------------------------------
// Apply attention via single-bf16 MFMA.  out: ((b*96 + w)*96 + h)*256 + c
// which=0 (block b, xi=w): O[h][c]  = sum_h2 Pms[b,h,h2] * V[b,h2,xi,c]
// which=1 (block b, xi=h): O[w][c] += sum_w2 Pma[b,w,w2] * V[b,xi,w2,c]
// M=96, N=256, K=96.  4 waves (2x2) of 48x128.  V transposed into LDS [c][k].
// ---------------------------------------------------------------------------
__global__ __launch_bounds__(256) void attn_apply_mfma(
    const ushort* __restrict__ vb, const ushort* __restrict__ P,
    float* __restrict__ out, const int which) {
  __shared__ ushort Vt[256 * 40];      // [c][k] stride 40 (80B, 16B-mult)
  const int tid = threadIdx.x;
  const int lane = tid & 63;
  const int wid = tid >> 6;
  const int wm = wid >> 1, wn = wid & 1;
  const int lr = lane & 15, quad = lane >> 4;
  const int xi = blockIdx.x;           // w (which=0) or h (which=1)
  const int b = blockIdx.y;

  f32x4 acc[3][8] = {};

  for (int k0 = 0; k0 < 96; k0 += 32) {
    // stage V-tile (32 k x 256 c) transposed via 2x2 micro-blocks
#pragma unroll
    for (int j = 0; j < 8; ++j) {
      int bi = j * 256 + tid;          // 0..2047
      int c2 = bi & 127;               // c-pair index
      int k2 = bi >> 7;                // k-pair index 0..15
      int k = k0 + k2 * 2;
      int c = c2 * 2;
      size_t r0, r1;
      if (which == 0) {
        r0 = ((size_t)b * HWQ + (size_t)k * SQ + xi) * CQ + c;
        r1 = r0 + (size_t)SQ * CQ;
      } else {
        r0 = ((size_t)b * HWQ + (size_t)xi * SQ + k) * CQ + c;
        r1 = r0 + CQ;
      }
      uint32_t a0 = *(const uint32_t*)(vb + r0);       // V[k][c], V[k][c+1]
      uint32_t a1 = *(const uint32_t*)(vb + r1);       // V[k+1][c], V[k+1][c+1]
      uint32_t w0 = (a0 & 0xFFFFu) | (a1 << 16);       // Vt[c][k..k+1]
      uint32_t w1 = (a0 >> 16) | (a1 & 0xFFFF0000u);   // Vt[c+1][k..k+1]
      *(uint32_t*)&Vt[c * 40 + k2 * 2] = w0;
      *(uint32_t*)&Vt[(c + 1) * 40 + k2 * 2] = w1;
    }
    __syncthreads();
    // A frags straight from global P (L1/L2-hot, reused by 96 blocks)
    FragU a[3];
#pragma unroll
    for (int t = 0; t < 3; ++t) {
      int row = wm * 48 + t * 16 + lr;
      const ushort* ps = P + ((size_t)b * SQ + row) * SQ + k0 + quad * 8;
      a[t].u = *(const uint4*)ps;
    }
#pragma unroll
    for (int j = 0; j < 8; ++j) {
      int cb = wn * 128 + j * 16 + lr;
      FragU bf;
      bf.u = *(const uint4*)&Vt[cb * 40 + quad * 8];
#pragma unroll
      for (int i = 0; i < 3; ++i)
        acc[i][j] = __builtin_amdgcn_mfma_f32_16x16x32_bf16(a[i].b, bf.b, acc[i][j], 0, 0, 0);
    }
    __syncthreads();
  }

#pragma unroll
  for (int i = 0; i < 3; ++i) {
#pragma unroll
    for (int r = 0; r < 4; ++r) {
      int mrow = wm * 48 + i * 16 + quad * 4 + r;
      size_t obase;
      if (which == 0) obase = (((size_t)b * SQ + xi) * SQ + mrow) * CQ;
      else            obase = (((size_t)b * SQ + mrow) * SQ + xi) * CQ;
#pragma unroll
      for (int j = 0; j < 8; ++j) {
        int c = wn * 128 + j * 16 + lr;
        if (which == 0) out[obase + c] = acc[i][j][r];
        else            out[obase + c] += acc[i][j][r];
      }
    }
  }
}

// ---------------------------------------------------------------------------
extern "C" void kernel_launch(void* const* d_in, const int* in_sizes, int n_in,
                              void* d_out, int out_size, void* d_ws,
                              size_t ws_size, hipStream_t stream) {
  const float* x = (const float*)d_in[0];      // (8,96,96,256) = (B,W,H,C)
  const float* w = (const float*)d_in[1];      // (768,256)
  const float* bias = (const float*)d_in[2];   // (768,)
  float* out = (float*)d_out;                  // (8,96,96,256) = (B,W,H,C)

  // workspace layout (~190 MB)
  ushort* qkh = (ushort*)d_ws;                           // 73728*512 ushort
  ushort* qkl = qkh + (size_t)PIXQ * 512;                // 73728*512 ushort
  ushort* vb  = qkl + (size_t)PIXQ * 512;                // 73728*256 ushort
  float*  Sh  = (float*)(vb + (size_t)PIXQ * 256);       // 73728 f32
  float*  Sw  = Sh + PIXQ;                               // 73728 f32
  ushort* Pms = (ushort*)(Sw + PIXQ);                    // 73728 ushort
  ushort* Pma = Pms + PIXQ;                              // 73728 ushort
  uint32_t* wps = (uint32_t*)(Pma + PIXQ);               // 196608 u32

  // x tile-image scratch lives in d_out (same 75.5 MB; out is written only
  // by the final apply kernels, long after the GEMM has consumed xps).
  uint32_t* xps = (uint32_t*)d_out;

  hipMemsetAsync(Sh, 0, 2 * (size_t)PIXQ * sizeof(float), stream);

  split_tiles_kernel<<<dim3(9216), 256, 0, stream>>>(x, xps);
  split_tiles_kernel<<<dim3(96), 256, 0, stream>>>(w, wps);
  qkv_gemm_mfma<<<dim3(3456), 256, 0, stream>>>(xps, wps, bias, qkh, qkl, vb);
  attn_scores_mfma<<<dim3(32, 8, 2), 256, 0, stream>>>(qkh, qkl, Sh, Sw);
  softmax_p<<<dim3(384), 256, 0, stream>>>(Sh, Sw, Pms, Pma);
  attn_apply_mfma<<<dim3(96, 8), 256, 0, stream>>>(vb, Pms, out, 0);
  attn_apply_mfma<<<dim3(96, 8), 256, 0, stream>>>(vb, Pma, out, 1);
}